// Round 7
// baseline (336.104 us; speedup 1.0000x reference)
//
#include <hip/hip_runtime.h>
#include <stdint.h>

#define N_NODES 10000
#define F_IN    512
#define E_DIM   256
#define H0D     512
#define H1D     256
#define N_EDGES 160000
#define T_TOT   (N_EDGES + N_NODES)   // 170000

#define MARGIN_LK 4e-3f
#define MARGIN_L  4e-3f
#define LIST_CAP 20000
#define FIX_GRID 1024
#define LP 40                       // padded LDS row stride in f16 (80B)

typedef _Float16 f16;
typedef __attribute__((ext_vector_type(8))) _Float16 f16x8;
typedef __attribute__((ext_vector_type(4))) _Float16 f16x4;
typedef __attribute__((ext_vector_type(4))) float f32x4;

// monotone map fp32 -> uint32 (order-preserving)
__device__ __forceinline__ unsigned int f2ord(float f) {
    unsigned int u = __float_as_uint(f);
    return (u & 0x80000000u) ? ~u : (u | 0x80000000u);
}
__device__ __forceinline__ float ord2f(unsigned int o) {
    unsigned int u = (o & 0x80000000u) ? (o & 0x7fffffffu) : ~o;
    return __uint_as_float(u);
}

// ---------------------------------------------------------------------------
// K_PREP_ALL: weight matrices -> chunked n-major split-f16 images + fp32 W1T.
// blocks 0-15: We; 16-31: W1; 32-63: W0 (4 groups x 8 chunks);
// blocks 64-95: W1T[j][k] = W1[k][j]  (fp32 transpose for the exact fixup).
//   img[c][n][kk] = split(W[rowoff + c*32 + kk][colbase + n])
// ---------------------------------------------------------------------------
__global__ void k_prep_all(const float* __restrict__ We,
                           const float* __restrict__ W1,
                           const float* __restrict__ W0,
                           f16* __restrict__ WeC_h, f16* __restrict__ WeC_l,
                           f16* __restrict__ W1C_h, f16* __restrict__ W1C_l,
                           f16* __restrict__ W0C_h, f16* __restrict__ W0C_l,
                           float* __restrict__ W1T) {
    int b = blockIdx.x;
    int n = threadIdx.x;
    if (b >= 64) {
        int j = (b - 64) * 8 + (n >> 5);
        int k0 = (n & 31) * 16;
#pragma unroll
        for (int kk = 0; kk < 16; kk++)
            W1T[(size_t)j * 512 + k0 + kk] = W1[(size_t)(k0 + kk) * H1D + j];
        return;
    }
    const float* W;
    int ld, rowoff, colbase, c;
    f16 *dh_base, *dl_base;
    if (b < 16) {
        W = We; ld = E_DIM; rowoff = 0; colbase = 0; c = b;
        dh_base = WeC_h; dl_base = WeC_l;
    } else if (b < 32) {
        W = W1; ld = H1D; rowoff = 0; colbase = 0; c = b - 16;
        dh_base = W1C_h; dl_base = W1C_l;
    } else {
        int g = (b - 32) >> 3; c = (b - 32) & 7;
        rowoff = (g >= 2) ? 256 : 0; colbase = (g & 1) * 256;
        W = W0; ld = H0D;
        dh_base = W0C_h + (size_t)g * 8 * 256 * 32;
        dl_base = W0C_l + (size_t)g * 8 * 256 * 32;
    }
    f16* dh = dh_base + ((size_t)c * 256 + n) * 32;
    f16* dl = dl_base + ((size_t)c * 256 + n) * 32;
    const float* src = W + (size_t)(rowoff + c * 32) * ld + colbase + n;
#pragma unroll
    for (int kk = 0; kk < 32; kk++) {
        float w = src[(size_t)kk * ld];
        f16 h = (f16)w;
        f16 l = (f16)(w - (float)h);
        dh[kk] = h;
        dl[kk] = l;
    }
}

// ---------------------------------------------------------------------------
// K1: Z = feature @ We + be (3-term split-f16, fp32-class);  out = relu(Z)
// 32-row tiles (313 blocks), register-B (no LDS for B), A-only LDS.
// Wave tile 32x64 = 2x4 MFMA 16x16x32.
// ---------------------------------------------------------------------------
__global__ __launch_bounds__(256, 2) void k1_split(
        const float* __restrict__ feat, const f16* __restrict__ Bh_g,
        const f16* __restrict__ Bl_g, const float* __restrict__ be,
        float* __restrict__ Z, float* __restrict__ out) {
    __shared__ f16 Ah[32 * LP], Al_[32 * LP];
    const int tid = threadIdx.x;
    const int wave = tid >> 6, lane = tid & 63;
    const int quad = lane >> 4, l15 = lane & 15;
    const int mbase = blockIdx.x * 32;
    const int arow = tid >> 3, apos = tid & 7;   // 32 rows x 8 thr, 4 fp32 each
    const int gm_a = mbase + arow;
    const float* Arow = feat + (size_t)gm_a * F_IN + apos * 4;
    const bool rowok = (gm_a < N_NODES);

    f32x4 acc[2][4];
#pragma unroll
    for (int i = 0; i < 2; i++)
#pragma unroll
        for (int j = 0; j < 4; j++) acc[i][j] = (f32x4){0.f, 0.f, 0.f, 0.f};

    // B fragment addresses: lane-owned, direct from global (L2)
    f16x8 bh[4], bl[4], bhn[4], bln[4];
#pragma unroll
    for (int ct = 0; ct < 4; ct++) {
        size_t o = ((size_t)(wave * 64 + ct * 16 + l15)) * 32 + quad * 8;
        bh[ct] = *(const f16x8*)(Bh_g + o);
        bl[ct] = *(const f16x8*)(Bl_g + o);
    }
    float4 a = rowok ? *(const float4*)(Arow) : make_float4(0.f, 0.f, 0.f, 0.f);

    for (int c = 0; c < 16; c++) {
        f16x4 hv, lv;
        float av[4] = {a.x, a.y, a.z, a.w};
#pragma unroll
        for (int q = 0; q < 4; q++) {
            f16 h = (f16)av[q];
            hv[q] = h;
            lv[q] = (f16)(av[q] - (float)h);
        }
        *(f16x4*)(Ah + arow * LP + apos * 4) = hv;
        *(f16x4*)(Al_ + arow * LP + apos * 4) = lv;
        if (c + 1 < 16) {
            a = rowok ? *(const float4*)(Arow + (c + 1) * 32)
                      : make_float4(0.f, 0.f, 0.f, 0.f);
#pragma unroll
            for (int ct = 0; ct < 4; ct++) {
                size_t o = ((size_t)((c + 1) * 256 + wave * 64 + ct * 16 + l15)) * 32 + quad * 8;
                bhn[ct] = *(const f16x8*)(Bh_g + o);
                bln[ct] = *(const f16x8*)(Bl_g + o);
            }
        }
        __syncthreads();
        f16x8 afh[2], afl[2];
#pragma unroll
        for (int rt = 0; rt < 2; rt++) {
            afh[rt] = *(const f16x8*)(Ah + (rt * 16 + l15) * LP + quad * 8);
            afl[rt] = *(const f16x8*)(Al_ + (rt * 16 + l15) * LP + quad * 8);
        }
#pragma unroll
        for (int rt = 0; rt < 2; rt++)
#pragma unroll
            for (int ct = 0; ct < 4; ct++) {
                acc[rt][ct] = __builtin_amdgcn_mfma_f32_16x16x32_f16(
                    afh[rt], bh[ct], acc[rt][ct], 0, 0, 0);
                acc[rt][ct] = __builtin_amdgcn_mfma_f32_16x16x32_f16(
                    afl[rt], bh[ct], acc[rt][ct], 0, 0, 0);
                acc[rt][ct] = __builtin_amdgcn_mfma_f32_16x16x32_f16(
                    afh[rt], bl[ct], acc[rt][ct], 0, 0, 0);
            }
        __syncthreads();
#pragma unroll
        for (int ct = 0; ct < 4; ct++) { bh[ct] = bhn[ct]; bl[ct] = bln[ct]; }
    }

#pragma unroll
    for (int ct = 0; ct < 4; ct++) {
        int n = wave * 64 + ct * 16 + l15;
        float bb = be[n];
#pragma unroll
        for (int rt = 0; rt < 2; rt++)
#pragma unroll
            for (int reg = 0; reg < 4; reg++) {
                int gm = mbase + rt * 16 + quad * 4 + reg;
                if (gm < N_NODES) {
                    float z = acc[rt][ct][reg] + bb;
                    Z[(size_t)gm * E_DIM + n] = z;
                    out[(size_t)gm * E_DIM + n] = fmaxf(z, 0.f);
                }
            }
    }
}

// ---------------------------------------------------------------------------
// K2: Pf = f16(emb @ W0[0:256,:] + b0) ; Qf = f16(emb @ W0[256:512,:])
// 3-term split-f16 (fp32-class before rounding). Register-B, A-only LDS.
// fp32 P/Q no longer stored (fixup recomputes from emb+W0 exactly).
// ---------------------------------------------------------------------------
__global__ __launch_bounds__(256, 3) void k2_split(
        const float* __restrict__ emb, const f16* __restrict__ W0Ch,
        const f16* __restrict__ W0Cl, const float* __restrict__ b0,
        f16* __restrict__ Pf, f16* __restrict__ Qf) {
    __shared__ f16 Ah[64 * LP], Al_[64 * LP];
    const int tid = threadIdx.x;
    const int wave = tid >> 6, lane = tid & 63;
    const int quad = lane >> 4, l15 = lane & 15;
    const int mbase = blockIdx.x * 64;
    const int g = blockIdx.y;
    const int isQ = (g >= 2);
    const int colbase = (g & 1) * 256;
    const int arow = tid >> 2, akp = tid & 3;    // 64 rows x 4 thr, 8 fp32 each
    const int gm_a = mbase + arow;
    const float* Arow = emb + (size_t)gm_a * E_DIM + akp * 8;
    const bool rowok = (gm_a < N_NODES);
    const f16* Bh_g = W0Ch + (size_t)g * 8 * 256 * 32;
    const f16* Bl_g = W0Cl + (size_t)g * 8 * 256 * 32;

    f32x4 acc[4][4];
#pragma unroll
    for (int i = 0; i < 4; i++)
#pragma unroll
        for (int j = 0; j < 4; j++) acc[i][j] = (f32x4){0.f, 0.f, 0.f, 0.f};

    f16x8 bh[4], bl[4], bhn[4], bln[4];
#pragma unroll
    for (int ct = 0; ct < 4; ct++) {
        size_t o = ((size_t)(wave * 64 + ct * 16 + l15)) * 32 + quad * 8;
        bh[ct] = *(const f16x8*)(Bh_g + o);
        bl[ct] = *(const f16x8*)(Bl_g + o);
    }
    float4 a0 = make_float4(0.f, 0.f, 0.f, 0.f), a1 = a0;
    if (rowok) { a0 = *(const float4*)(Arow); a1 = *(const float4*)(Arow + 4); }

    for (int c = 0; c < 8; c++) {
        f16x8 hv, lv;
        float av[8] = {a0.x, a0.y, a0.z, a0.w, a1.x, a1.y, a1.z, a1.w};
#pragma unroll
        for (int q = 0; q < 8; q++) {
            f16 h = (f16)av[q];
            hv[q] = h;
            lv[q] = (f16)(av[q] - (float)h);
        }
        *(f16x8*)(Ah + arow * LP + akp * 8) = hv;
        *(f16x8*)(Al_ + arow * LP + akp * 8) = lv;
        if (c + 1 < 8) {
            if (rowok) {
                a0 = *(const float4*)(Arow + (c + 1) * 32);
                a1 = *(const float4*)(Arow + (c + 1) * 32 + 4);
            }
#pragma unroll
            for (int ct = 0; ct < 4; ct++) {
                size_t o = ((size_t)((c + 1) * 256 + wave * 64 + ct * 16 + l15)) * 32 + quad * 8;
                bhn[ct] = *(const f16x8*)(Bh_g + o);
                bln[ct] = *(const f16x8*)(Bl_g + o);
            }
        }
        __syncthreads();
        f16x8 afh[4], afl[4];
#pragma unroll
        for (int rt = 0; rt < 4; rt++) {
            afh[rt] = *(const f16x8*)(Ah + (rt * 16 + l15) * LP + quad * 8);
            afl[rt] = *(const f16x8*)(Al_ + (rt * 16 + l15) * LP + quad * 8);
        }
#pragma unroll
        for (int rt = 0; rt < 4; rt++)
#pragma unroll
            for (int ct = 0; ct < 4; ct++) {
                acc[rt][ct] = __builtin_amdgcn_mfma_f32_16x16x32_f16(
                    afh[rt], bh[ct], acc[rt][ct], 0, 0, 0);
                acc[rt][ct] = __builtin_amdgcn_mfma_f32_16x16x32_f16(
                    afl[rt], bh[ct], acc[rt][ct], 0, 0, 0);
                acc[rt][ct] = __builtin_amdgcn_mfma_f32_16x16x32_f16(
                    afh[rt], bl[ct], acc[rt][ct], 0, 0, 0);
            }
        __syncthreads();
#pragma unroll
        for (int ct = 0; ct < 4; ct++) { bh[ct] = bhn[ct]; bl[ct] = bln[ct]; }
    }

    f16* dstf = isQ ? Qf : Pf;
#pragma unroll
    for (int ct = 0; ct < 4; ct++) {
        int n = wave * 64 + ct * 16 + l15;
        float bb = isQ ? 0.f : b0[colbase + n];
#pragma unroll
        for (int rt = 0; rt < 4; rt++)
#pragma unroll
            for (int reg = 0; reg < 4; reg++) {
                int gm = mbase + rt * 16 + quad * 4 + reg;
                if (gm < N_NODES)
                    dstf[(size_t)gm * H0D + colbase + n] = (f16)(acc[rt][ct][reg] + bb);
            }
    }
}

// ---------------------------------------------------------------------------
// K3 (1-term, f16 gather, register-B, A-only LDS): h1 = relu(Pf[s]+Qf[d]);
// h = relu(h1@W1h+b1); lk + logits (~1e-3-class). atomicMax (lk,t) per seg.
// ---------------------------------------------------------------------------
__global__ __launch_bounds__(256, 3) void k3_f16(
        const f16* __restrict__ Pf, const f16* __restrict__ Qf,
        const f16* __restrict__ W1Bh, const float* __restrict__ b1,
        const float* __restrict__ Wlk, const float* __restrict__ blkp,
        const float* __restrict__ Wa, const float* __restrict__ ba,
        const int* __restrict__ esrc, const int* __restrict__ edst,
        unsigned long long* __restrict__ keys, float* __restrict__ lk_app,
        float* __restrict__ logits) {
    __shared__ f16 Ah[64 * LP];
    __shared__ float redA[64][5], redB[64][5], redC[64][5];
    __shared__ int s_seg[64], s_dst[64];
    const int tid = threadIdx.x;
    const int wave = tid >> 6, lane = tid & 63;
    const int quad = lane >> 4, l15 = lane & 15;
    const int tbase = blockIdx.x * 64;

    if (tid < 64) {
        int t = tbase + tid;
        int s = 0, d = -1;
        if (t < N_EDGES) { s = esrc[t]; d = edst[t]; }
        else if (t < T_TOT) { s = t - N_EDGES; }
        s_seg[tid] = s;
        s_dst[tid] = d;
    }
    __syncthreads();

    const int arow = tid >> 2, akp = tid & 3;
    const int sA = s_seg[arow], dA = s_dst[arow];
    const f16* Prow = Pf + (size_t)sA * H0D + akp * 8;
    const f16* Qrow = Qf + (size_t)(dA >= 0 ? dA : 0) * H0D + akp * 8;
    const bool hasQ = (dA >= 0);
    const f16x8 zero8 = (f16x8)(f16)0;

    f32x4 acc[4][4];
#pragma unroll
    for (int i = 0; i < 4; i++)
#pragma unroll
        for (int j = 0; j < 4; j++) acc[i][j] = (f32x4){0.f, 0.f, 0.f, 0.f};

    // prologue: chunk 0 loads
    f16x8 pa = *(const f16x8*)(Prow);
    f16x8 qa = hasQ ? *(const f16x8*)(Qrow) : zero8;
    f16x8 bf[4], bfn[4];
#pragma unroll
    for (int ct = 0; ct < 4; ct++)
        bf[ct] = *(const f16x8*)(W1Bh + ((size_t)(wave * 64 + ct * 16 + l15)) * 32 + quad * 8);

    for (int c = 0; c < 16; c++) {
        f16x8 hv;
#pragma unroll
        for (int q = 0; q < 8; q++) {
            f16 s = pa[q] + qa[q];
            hv[q] = (s > (f16)0) ? s : (f16)0;
        }
        *(f16x8*)(Ah + arow * LP + akp * 8) = hv;
        if (c + 1 < 16) {
            pa = *(const f16x8*)(Prow + (c + 1) * 32);
            qa = hasQ ? *(const f16x8*)(Qrow + (c + 1) * 32) : zero8;
#pragma unroll
            for (int ct = 0; ct < 4; ct++)
                bfn[ct] = *(const f16x8*)(W1Bh +
                    ((size_t)((c + 1) * 256 + wave * 64 + ct * 16 + l15)) * 32 + quad * 8);
        }
        __syncthreads();
        f16x8 af[4];
#pragma unroll
        for (int rt = 0; rt < 4; rt++)
            af[rt] = *(const f16x8*)(Ah + (rt * 16 + l15) * LP + quad * 8);
#pragma unroll
        for (int rt = 0; rt < 4; rt++)
#pragma unroll
            for (int ct = 0; ct < 4; ct++)
                acc[rt][ct] = __builtin_amdgcn_mfma_f32_16x16x32_f16(
                    af[rt], bf[ct], acc[rt][ct], 0, 0, 0);
        __syncthreads();
#pragma unroll
        for (int ct = 0; ct < 4; ct++) bf[ct] = bfn[ct];
    }

    // epilogue: h = relu(acc + b1); three 256-dots (lk, logit0, logit1)
    float wl[4], wa0[4], wa1[4], bb[4];
#pragma unroll
    for (int ct = 0; ct < 4; ct++) {
        int n = wave * 64 + ct * 16 + l15;
        wl[ct] = Wlk[n];
        wa0[ct] = Wa[2 * n];
        wa1[ct] = Wa[2 * n + 1];
        bb[ct] = b1[n];
    }
#pragma unroll
    for (int rt = 0; rt < 4; rt++) {
#pragma unroll
        for (int reg = 0; reg < 4; reg++) {
            float plk = 0.f, p0 = 0.f, p1 = 0.f;
#pragma unroll
            for (int ct = 0; ct < 4; ct++) {
                float h = fmaxf(acc[rt][ct][reg] + bb[ct], 0.f);
                plk = fmaf(h, wl[ct], plk);
                p0 = fmaf(h, wa0[ct], p0);
                p1 = fmaf(h, wa1[ct], p1);
            }
#pragma unroll
            for (int off = 8; off >= 1; off >>= 1) {
                plk += __shfl_xor(plk, off);
                p0 += __shfl_xor(p0, off);
                p1 += __shfl_xor(p1, off);
            }
            if (l15 == 0) {
                int row = rt * 16 + quad * 4 + reg;
                redA[row][wave] = plk;
                redB[row][wave] = p0;
                redC[row][wave] = p1;
            }
        }
    }
    __syncthreads();
    if (tid < 64) {
        int t = tbase + tid;
        if (t < T_TOT) {
            float lk = redA[tid][0] + redA[tid][1] + redA[tid][2] + redA[tid][3] + blkp[0];
            float l0 = redB[tid][0] + redB[tid][1] + redB[tid][2] + redB[tid][3] + ba[0];
            float l1 = redC[tid][0] + redC[tid][1] + redC[tid][2] + redC[tid][3] + ba[1];
            lk_app[t] = lk;
            logits[2 * t] = l0;
            logits[2 * t + 1] = l1;
            unsigned long long key =
                ((unsigned long long)f2ord(lk) << 32) | (unsigned int)t;
            atomicMax(keys + s_seg[tid], key);
        }
    }
}

// ---------------------------------------------------------------------------
// K_GB: gather (a) challengers within MARGIN_LK of their segment best plus the
// segment's approx winner; (b) approx winners whose logit gap < MARGIN_L.
// ---------------------------------------------------------------------------
__global__ void k_gb(const float* __restrict__ lk_app,
                     const unsigned long long* __restrict__ keys,
                     const int* __restrict__ esrc,
                     const float* __restrict__ logits,
                     int* __restrict__ list, int* __restrict__ count) {
    int t = blockIdx.x * 256 + threadIdx.x;
    if (t < T_TOT) {
        int seg = (t < N_EDGES) ? esrc[t] : t - N_EDGES;
        unsigned long long k = keys[seg];
        int tw = (int)(k & 0xFFFFFFFFull);
        if (t != tw) {
            float best = ord2f((unsigned int)(k >> 32));
            if (lk_app[t] >= best - MARGIN_LK) {
                int idx = atomicAdd(count, 2);
                if (idx + 1 < LIST_CAP) { list[idx] = t; list[idx + 1] = tw; }
            }
        }
    }
    if (t < N_NODES) {
        int tw = (int)(keys[t] & 0xFFFFFFFFull);
        float g = fabsf(logits[2 * tw + 1] - logits[2 * tw]);
        if (g < MARGIN_L) {
            int idx = atomicAdd(count, 1);
            if (idx < LIST_CAP) list[idx] = tw;
        }
    }
}

// ---------------------------------------------------------------------------
// K_FIXUP (latency-shaped, emb-based): one block per entry. Exact fp32:
// h1 = relu(b0 + emb_s@W0_top + emb_d@W0_bot); h = relu(h1@W1+b1) via W1T;
// lk/logits reduced block-wide. Replaces the dropped fp32 P/Q.
// ---------------------------------------------------------------------------
__global__ __launch_bounds__(256, 4) void k_fixup(
        const float* __restrict__ emb, const float* __restrict__ W0,
        const float* __restrict__ b0, const float* __restrict__ W1T,
        const float* __restrict__ b1, const float* __restrict__ Wlk,
        const float* __restrict__ blkp, const float* __restrict__ Wa,
        const float* __restrict__ ba, const int* __restrict__ esrc,
        const int* __restrict__ edst, const int* __restrict__ list,
        const int* __restrict__ count, unsigned long long* __restrict__ keys2,
        float* __restrict__ logits) {
    __shared__ float embs[256], embd[256];
    __shared__ float h1[512];
    __shared__ float red[3][4];
    const int tid = threadIdx.x;
    int cnt = *count;
    if (cnt > LIST_CAP) cnt = LIST_CAP;

    const float bb1 = b1[tid];
    const float wl = Wlk[tid];
    const float w0a = Wa[2 * tid];
    const float w1a = Wa[2 * tid + 1];
    const float* wrow = W1T + (size_t)tid * 512;
    const float bb0a = b0[tid];
    const float bb0b = b0[tid + 256];

    for (int e = blockIdx.x; e < cnt; e += gridDim.x) {
        int t = list[e];
        if (t < 0 || t >= T_TOT) continue;
        int s, d;
        if (t < N_EDGES) { s = esrc[t]; d = edst[t]; }
        else { s = t - N_EDGES; d = -1; }

        embs[tid] = emb[(size_t)s * E_DIM + tid];
        embd[tid] = (d >= 0) ? emb[(size_t)d * E_DIM + tid] : 0.f;
        __syncthreads();

        // h1[k] for k = tid, tid+256  (exact fp32 as in reference)
        float acc0 = bb0a, acc1 = bb0b;
        for (int j = 0; j < 256; j++) {
            float es = embs[j];
            float ed = embd[j];
            acc0 = fmaf(es, W0[(size_t)j * H0D + tid], acc0);
            acc1 = fmaf(es, W0[(size_t)j * H0D + tid + 256], acc1);
            acc0 = fmaf(ed, W0[(size_t)(256 + j) * H0D + tid], acc0);
            acc1 = fmaf(ed, W0[(size_t)(256 + j) * H0D + tid + 256], acc1);
        }
        h1[tid] = fmaxf(acc0, 0.f);
        h1[tid + 256] = fmaxf(acc1, 0.f);
        __syncthreads();

        // h[j] = relu(h1 . W1T[j] + b1[j]); three head dots
        float a0 = 0.f, a1 = 0.f, a2 = 0.f, a3 = 0.f;
        for (int k = 0; k < 512; k += 16) {
            float4 wv0 = *(const float4*)(wrow + k);
            float4 wv1 = *(const float4*)(wrow + k + 4);
            float4 wv2 = *(const float4*)(wrow + k + 8);
            float4 wv3 = *(const float4*)(wrow + k + 12);
            float4 hv0 = *(const float4*)(h1 + k);
            float4 hv1 = *(const float4*)(h1 + k + 4);
            float4 hv2 = *(const float4*)(h1 + k + 8);
            float4 hv3 = *(const float4*)(h1 + k + 12);
            a0 = fmaf(hv0.x, wv0.x, a0); a0 = fmaf(hv0.y, wv0.y, a0);
            a0 = fmaf(hv0.z, wv0.z, a0); a0 = fmaf(hv0.w, wv0.w, a0);
            a1 = fmaf(hv1.x, wv1.x, a1); a1 = fmaf(hv1.y, wv1.y, a1);
            a1 = fmaf(hv1.z, wv1.z, a1); a1 = fmaf(hv1.w, wv1.w, a1);
            a2 = fmaf(hv2.x, wv2.x, a2); a2 = fmaf(hv2.y, wv2.y, a2);
            a2 = fmaf(hv2.z, wv2.z, a2); a2 = fmaf(hv2.w, wv2.w, a2);
            a3 = fmaf(hv3.x, wv3.x, a3); a3 = fmaf(hv3.y, wv3.y, a3);
            a3 = fmaf(hv3.z, wv3.z, a3); a3 = fmaf(hv3.w, wv3.w, a3);
        }
        float hj = fmaxf((a0 + a1) + (a2 + a3) + bb1, 0.f);
        float plk = hj * wl;
        float p0 = hj * w0a;
        float p1 = hj * w1a;
#pragma unroll
        for (int off = 32; off >= 1; off >>= 1) {
            plk += __shfl_xor(plk, off);
            p0 += __shfl_xor(p0, off);
            p1 += __shfl_xor(p1, off);
        }
        int wv = tid >> 6;
        if ((tid & 63) == 0) {
            red[0][wv] = plk; red[1][wv] = p0; red[2][wv] = p1;
        }
        __syncthreads();
        if (tid == 0) {
            float lk = red[0][0] + red[0][1] + red[0][2] + red[0][3] + blkp[0];
            float l0 = red[1][0] + red[1][1] + red[1][2] + red[1][3] + ba[0];
            float l1 = red[2][0] + red[2][1] + red[2][2] + red[2][3] + ba[1];
            logits[2 * t] = l0;
            logits[2 * t + 1] = l1;
            unsigned long long key =
                ((unsigned long long)f2ord(lk) << 32) | (unsigned int)t;
            atomicMax(keys2 + s, key);
        }
        __syncthreads();
    }
}

// ---------------------------------------------------------------------------
// K4: winner per node (keys2 if exact candidates exist, else approx keys);
// at-bit from logits; last-writer claim (+1 coded).
// ---------------------------------------------------------------------------
__global__ void k4_select(const unsigned long long* __restrict__ keys,
                          const unsigned long long* __restrict__ keys2,
                          const int* __restrict__ edst,
                          const float* __restrict__ logits,
                          int* __restrict__ chosen_arr,
                          int* __restrict__ tgt_writer) {
    int i = blockIdx.x * 256 + threadIdx.x;
    if (i >= N_NODES) return;
    unsigned long long key = keys[i];
    unsigned long long k2v = keys2[i];
    if (k2v != 0ull) key = k2v;
    int t = (int)(key & 0xFFFFFFFFull);
    int chosen = (t < N_EDGES) ? edst[t] : -1;
    float lg0 = logits[2 * t], lg1 = logits[2 * t + 1];
    int at1 = (lg1 > lg0) ? 1 : 0;   // argmax: tie -> index 0
    int c = (chosen >= 0 && at1) ? chosen : -1;
    chosen_arr[i] = c;
    if (c >= 0) atomicMax(tgt_writer + c, i + 1);   // last-write-wins: max i
}

// ---------------------------------------------------------------------------
// K5: winning writers update rows: out[c] = relu(0.5*(Z[i] + Z[c]))
// ---------------------------------------------------------------------------
__global__ void k5_update(const int* __restrict__ chosen_arr,
                          const int* __restrict__ tgt_writer,
                          const float* __restrict__ Z,
                          float* __restrict__ out) {
    int i = blockIdx.x;
    int c = chosen_arr[i];
    if (c < 0 || tgt_writer[c] != i + 1) return;
    int n = threadIdx.x;
    float z = 0.5f * (Z[(size_t)i * E_DIM + n] + Z[(size_t)c * E_DIM + n]);
    out[(size_t)c * E_DIM + n] = fmaxf(z, 0.f);
}

// ---------------------------------------------------------------------------
extern "C" void kernel_launch(void* const* d_in, const int* in_sizes, int n_in,
                              void* d_out, int out_size, void* d_ws,
                              size_t ws_size, hipStream_t stream) {
    const float* feat = (const float*)d_in[0];
    const float* We   = (const float*)d_in[1];
    const float* be   = (const float*)d_in[2];
    const float* W0   = (const float*)d_in[3];
    const float* b0   = (const float*)d_in[4];
    const float* W1   = (const float*)d_in[5];
    const float* b1   = (const float*)d_in[6];
    const float* Wlk  = (const float*)d_in[7];
    const float* blkp = (const float*)d_in[8];
    const float* Wa   = (const float*)d_in[9];
    const float* ba   = (const float*)d_in[10];
    const int* esrc   = (const int*)d_in[11];
    const int* edst   = (const int*)d_in[12];
    float* out = (float*)d_out;

    char* ws = (char*)d_ws;
    size_t off = 0;
    float* Z  = (float*)(ws + off); off += (size_t)N_NODES * E_DIM * 4;
    f16* Pf   = (f16*)(ws + off);   off += (size_t)N_NODES * H0D * 2;
    f16* Qf   = (f16*)(ws + off);   off += (size_t)N_NODES * H0D * 2;
    // ---- contiguous zero-init region ----
    char* zero_base = ws + off;
    unsigned long long* keys  = (unsigned long long*)(ws + off); off += N_NODES * 8;
    unsigned long long* keys2 = (unsigned long long*)(ws + off); off += N_NODES * 8;
    int* tgt_writer = (int*)(ws + off); off += N_NODES * 4;   // +1 encoding, 0 = none
    int* count      = (int*)(ws + off); off += 128;
    size_t zero_bytes = (size_t)((ws + off) - zero_base);
    // -------------------------------------
    float* logits = (float*)(ws + off); off += (size_t)T_TOT * 2 * 4;
    float* lk_app = (float*)(ws + off); off += (size_t)T_TOT * 4;
    int* list     = (int*)(ws + off); off += (size_t)LIST_CAP * 4;
    int* chosen_arr = (int*)(ws + off); off += N_NODES * 4;
    f16* WeC_h = (f16*)(ws + off); off += (size_t)16 * 256 * 32 * 2;
    f16* WeC_l = (f16*)(ws + off); off += (size_t)16 * 256 * 32 * 2;
    f16* W1C_h = (f16*)(ws + off); off += (size_t)16 * 256 * 32 * 2;
    f16* W1C_l = (f16*)(ws + off); off += (size_t)16 * 256 * 32 * 2;
    f16* W0C_h = (f16*)(ws + off); off += (size_t)32 * 256 * 32 * 2;
    f16* W0C_l = (f16*)(ws + off); off += (size_t)32 * 256 * 32 * 2;
    float* W1T = (float*)(ws + off); off += (size_t)H1D * H0D * 4;   // 512 KB

    hipMemsetAsync(zero_base, 0, zero_bytes, stream);

    k_prep_all<<<dim3(96), 256, 0, stream>>>(
        We, W1, W0, WeC_h, WeC_l, W1C_h, W1C_l, W0C_h, W0C_l, W1T);
    k1_split<<<dim3((N_NODES + 31) / 32), 256, 0, stream>>>(
        feat, WeC_h, WeC_l, be, Z, out);
    k2_split<<<dim3((N_NODES + 63) / 64, 4), 256, 0, stream>>>(
        out, W0C_h, W0C_l, b0, Pf, Qf);
    k3_f16<<<dim3((T_TOT + 63) / 64), 256, 0, stream>>>(
        Pf, Qf, W1C_h, b1, Wlk, blkp, Wa, ba, esrc, edst,
        keys, lk_app, logits);
    k_gb<<<dim3((T_TOT + 255) / 256), 256, 0, stream>>>(
        lk_app, keys, esrc, logits, list, count);
    k_fixup<<<dim3(FIX_GRID), 256, 0, stream>>>(
        out, W0, b0, W1T, b1, Wlk, blkp, Wa, ba, esrc, edst,
        list, count, keys2, logits);
    k4_select<<<dim3((N_NODES + 255) / 256), 256, 0, stream>>>(
        keys, keys2, edst, logits, chosen_arr, tgt_writer);
    k5_update<<<dim3(N_NODES), 256, 0, stream>>>(chosen_arr, tgt_writer, Z, out);
}

// Round 8
// 268.662 us; speedup vs baseline: 1.2510x; 1.2510x over previous
//
#include <hip/hip_runtime.h>
#include <stdint.h>

#define N_NODES 10000
#define F_IN    512
#define E_DIM   256
#define H0D     512
#define H1D     256
#define N_EDGES 160000
#define T_TOT   (N_EDGES + N_NODES)   // 170000

#define MARGIN_LK 4e-3f
#define MARGIN_L  4e-3f
#define LIST_CAP 60000
#define FIX_GRID 512
#define LP 40                       // padded LDS row stride in f16 (80B)

typedef _Float16 f16;
typedef __attribute__((ext_vector_type(8))) _Float16 f16x8;
typedef __attribute__((ext_vector_type(4))) _Float16 f16x4;
typedef __attribute__((ext_vector_type(4))) float f32x4;

// monotone map fp32 -> uint32 (order-preserving)
__device__ __forceinline__ unsigned int f2ord(float f) {
    unsigned int u = __float_as_uint(f);
    return (u & 0x80000000u) ? ~u : (u | 0x80000000u);
}
__device__ __forceinline__ float ord2f(unsigned int o) {
    unsigned int u = (o & 0x80000000u) ? (o & 0x7fffffffu) : ~o;
    return __uint_as_float(u);
}

// ---------------------------------------------------------------------------
// K_PREP_ALL: weight matrices -> chunked n-major split-f16 images.
// blocks 0-15: We; 16-31: W1; 32-63: W0 (4 groups x 8 chunks).
//   img[c][n][kk] = split(W[rowoff + c*32 + kk][colbase + n])
// ---------------------------------------------------------------------------
__global__ void k_prep_all(const float* __restrict__ We,
                           const float* __restrict__ W1,
                           const float* __restrict__ W0,
                           f16* __restrict__ WeC_h, f16* __restrict__ WeC_l,
                           f16* __restrict__ W1C_h, f16* __restrict__ W1C_l,
                           f16* __restrict__ W0C_h, f16* __restrict__ W0C_l) {
    int b = blockIdx.x;
    int n = threadIdx.x;
    const float* W;
    int ld, rowoff, colbase, c;
    f16 *dh_base, *dl_base;
    if (b < 16) {
        W = We; ld = E_DIM; rowoff = 0; colbase = 0; c = b;
        dh_base = WeC_h; dl_base = WeC_l;
    } else if (b < 32) {
        W = W1; ld = H1D; rowoff = 0; colbase = 0; c = b - 16;
        dh_base = W1C_h; dl_base = W1C_l;
    } else {
        int g = (b - 32) >> 3; c = (b - 32) & 7;
        rowoff = (g >= 2) ? 256 : 0; colbase = (g & 1) * 256;
        W = W0; ld = H0D;
        dh_base = W0C_h + (size_t)g * 8 * 256 * 32;
        dl_base = W0C_l + (size_t)g * 8 * 256 * 32;
    }
    f16* dh = dh_base + ((size_t)c * 256 + n) * 32;
    f16* dl = dl_base + ((size_t)c * 256 + n) * 32;
    const float* src = W + (size_t)(rowoff + c * 32) * ld + colbase + n;
#pragma unroll
    for (int kk = 0; kk < 32; kk++) {
        float w = src[(size_t)kk * ld];
        f16 h = (f16)w;
        f16 l = (f16)(w - (float)h);
        dh[kk] = h;
        dl[kk] = l;
    }
}

// ---------------------------------------------------------------------------
// K1: Z = feature @ We + be (3-term split-f16, fp32-class);  out = relu(Z)
// 32-row tiles, register-B, A-only LDS.
// ---------------------------------------------------------------------------
__global__ __launch_bounds__(256, 2) void k1_split(
        const float* __restrict__ feat, const f16* __restrict__ Bh_g,
        const f16* __restrict__ Bl_g, const float* __restrict__ be,
        float* __restrict__ Z, float* __restrict__ out) {
    __shared__ f16 Ah[32 * LP], Al_[32 * LP];
    const int tid = threadIdx.x;
    const int wave = tid >> 6, lane = tid & 63;
    const int quad = lane >> 4, l15 = lane & 15;
    const int mbase = blockIdx.x * 32;
    const int arow = tid >> 3, apos = tid & 7;
    const int gm_a = mbase + arow;
    const float* Arow = feat + (size_t)gm_a * F_IN + apos * 4;
    const bool rowok = (gm_a < N_NODES);

    f32x4 acc[2][4];
#pragma unroll
    for (int i = 0; i < 2; i++)
#pragma unroll
        for (int j = 0; j < 4; j++) acc[i][j] = (f32x4){0.f, 0.f, 0.f, 0.f};

    f16x8 bh[4], bl[4], bhn[4], bln[4];
#pragma unroll
    for (int ct = 0; ct < 4; ct++) {
        size_t o = ((size_t)(wave * 64 + ct * 16 + l15)) * 32 + quad * 8;
        bh[ct] = *(const f16x8*)(Bh_g + o);
        bl[ct] = *(const f16x8*)(Bl_g + o);
    }
    float4 a = rowok ? *(const float4*)(Arow) : make_float4(0.f, 0.f, 0.f, 0.f);

    for (int c = 0; c < 16; c++) {
        f16x4 hv, lv;
        float av[4] = {a.x, a.y, a.z, a.w};
#pragma unroll
        for (int q = 0; q < 4; q++) {
            f16 h = (f16)av[q];
            hv[q] = h;
            lv[q] = (f16)(av[q] - (float)h);
        }
        *(f16x4*)(Ah + arow * LP + apos * 4) = hv;
        *(f16x4*)(Al_ + arow * LP + apos * 4) = lv;
        if (c + 1 < 16) {
            a = rowok ? *(const float4*)(Arow + (c + 1) * 32)
                      : make_float4(0.f, 0.f, 0.f, 0.f);
#pragma unroll
            for (int ct = 0; ct < 4; ct++) {
                size_t o = ((size_t)((c + 1) * 256 + wave * 64 + ct * 16 + l15)) * 32 + quad * 8;
                bhn[ct] = *(const f16x8*)(Bh_g + o);
                bln[ct] = *(const f16x8*)(Bl_g + o);
            }
        }
        __syncthreads();
        f16x8 afh[2], afl[2];
#pragma unroll
        for (int rt = 0; rt < 2; rt++) {
            afh[rt] = *(const f16x8*)(Ah + (rt * 16 + l15) * LP + quad * 8);
            afl[rt] = *(const f16x8*)(Al_ + (rt * 16 + l15) * LP + quad * 8);
        }
#pragma unroll
        for (int rt = 0; rt < 2; rt++)
#pragma unroll
            for (int ct = 0; ct < 4; ct++) {
                acc[rt][ct] = __builtin_amdgcn_mfma_f32_16x16x32_f16(
                    afh[rt], bh[ct], acc[rt][ct], 0, 0, 0);
                acc[rt][ct] = __builtin_amdgcn_mfma_f32_16x16x32_f16(
                    afl[rt], bh[ct], acc[rt][ct], 0, 0, 0);
                acc[rt][ct] = __builtin_amdgcn_mfma_f32_16x16x32_f16(
                    afh[rt], bl[ct], acc[rt][ct], 0, 0, 0);
            }
        __syncthreads();
#pragma unroll
        for (int ct = 0; ct < 4; ct++) { bh[ct] = bhn[ct]; bl[ct] = bln[ct]; }
    }

#pragma unroll
    for (int ct = 0; ct < 4; ct++) {
        int n = wave * 64 + ct * 16 + l15;
        float bb = be[n];
#pragma unroll
        for (int rt = 0; rt < 2; rt++)
#pragma unroll
            for (int reg = 0; reg < 4; reg++) {
                int gm = mbase + rt * 16 + quad * 4 + reg;
                if (gm < N_NODES) {
                    float z = acc[rt][ct][reg] + bb;
                    Z[(size_t)gm * E_DIM + n] = z;
                    out[(size_t)gm * E_DIM + n] = fmaxf(z, 0.f);
                }
            }
    }
}

// ---------------------------------------------------------------------------
// K2: P = emb @ W0[0:256,:] + b0 ; Q = emb @ W0[256:512,:]  (3-term exact)
// Stores SPLIT f16: Ph/Pl and Qh/Ql (Ph+Pl reconstructs fp32 P to ~2^-22).
// ---------------------------------------------------------------------------
__global__ __launch_bounds__(256, 3) void k2_split(
        const float* __restrict__ emb, const f16* __restrict__ W0Ch,
        const f16* __restrict__ W0Cl, const float* __restrict__ b0,
        f16* __restrict__ Ph, f16* __restrict__ Pl,
        f16* __restrict__ Qh, f16* __restrict__ Ql) {
    __shared__ f16 Ah[64 * LP], Al_[64 * LP];
    const int tid = threadIdx.x;
    const int wave = tid >> 6, lane = tid & 63;
    const int quad = lane >> 4, l15 = lane & 15;
    const int mbase = blockIdx.x * 64;
    const int g = blockIdx.y;
    const int isQ = (g >= 2);
    const int colbase = (g & 1) * 256;
    const int arow = tid >> 2, akp = tid & 3;
    const int gm_a = mbase + arow;
    const float* Arow = emb + (size_t)gm_a * E_DIM + akp * 8;
    const bool rowok = (gm_a < N_NODES);
    const f16* Bh_g = W0Ch + (size_t)g * 8 * 256 * 32;
    const f16* Bl_g = W0Cl + (size_t)g * 8 * 256 * 32;

    f32x4 acc[4][4];
#pragma unroll
    for (int i = 0; i < 4; i++)
#pragma unroll
        for (int j = 0; j < 4; j++) acc[i][j] = (f32x4){0.f, 0.f, 0.f, 0.f};

    f16x8 bh[4], bl[4], bhn[4], bln[4];
#pragma unroll
    for (int ct = 0; ct < 4; ct++) {
        size_t o = ((size_t)(wave * 64 + ct * 16 + l15)) * 32 + quad * 8;
        bh[ct] = *(const f16x8*)(Bh_g + o);
        bl[ct] = *(const f16x8*)(Bl_g + o);
    }
    float4 a0 = make_float4(0.f, 0.f, 0.f, 0.f), a1 = a0;
    if (rowok) { a0 = *(const float4*)(Arow); a1 = *(const float4*)(Arow + 4); }

    for (int c = 0; c < 8; c++) {
        f16x8 hv, lv;
        float av[8] = {a0.x, a0.y, a0.z, a0.w, a1.x, a1.y, a1.z, a1.w};
#pragma unroll
        for (int q = 0; q < 8; q++) {
            f16 h = (f16)av[q];
            hv[q] = h;
            lv[q] = (f16)(av[q] - (float)h);
        }
        *(f16x8*)(Ah + arow * LP + akp * 8) = hv;
        *(f16x8*)(Al_ + arow * LP + akp * 8) = lv;
        if (c + 1 < 8) {
            if (rowok) {
                a0 = *(const float4*)(Arow + (c + 1) * 32);
                a1 = *(const float4*)(Arow + (c + 1) * 32 + 4);
            }
#pragma unroll
            for (int ct = 0; ct < 4; ct++) {
                size_t o = ((size_t)((c + 1) * 256 + wave * 64 + ct * 16 + l15)) * 32 + quad * 8;
                bhn[ct] = *(const f16x8*)(Bh_g + o);
                bln[ct] = *(const f16x8*)(Bl_g + o);
            }
        }
        __syncthreads();
        f16x8 afh[4], afl[4];
#pragma unroll
        for (int rt = 0; rt < 4; rt++) {
            afh[rt] = *(const f16x8*)(Ah + (rt * 16 + l15) * LP + quad * 8);
            afl[rt] = *(const f16x8*)(Al_ + (rt * 16 + l15) * LP + quad * 8);
        }
#pragma unroll
        for (int rt = 0; rt < 4; rt++)
#pragma unroll
            for (int ct = 0; ct < 4; ct++) {
                acc[rt][ct] = __builtin_amdgcn_mfma_f32_16x16x32_f16(
                    afh[rt], bh[ct], acc[rt][ct], 0, 0, 0);
                acc[rt][ct] = __builtin_amdgcn_mfma_f32_16x16x32_f16(
                    afl[rt], bh[ct], acc[rt][ct], 0, 0, 0);
                acc[rt][ct] = __builtin_amdgcn_mfma_f32_16x16x32_f16(
                    afh[rt], bl[ct], acc[rt][ct], 0, 0, 0);
            }
        __syncthreads();
#pragma unroll
        for (int ct = 0; ct < 4; ct++) { bh[ct] = bhn[ct]; bl[ct] = bln[ct]; }
    }

    f16* dh = isQ ? Qh : Ph;
    f16* dl = isQ ? Ql : Pl;
#pragma unroll
    for (int ct = 0; ct < 4; ct++) {
        int n = wave * 64 + ct * 16 + l15;
        float bb = isQ ? 0.f : b0[colbase + n];
#pragma unroll
        for (int rt = 0; rt < 4; rt++)
#pragma unroll
            for (int reg = 0; reg < 4; reg++) {
                int gm = mbase + rt * 16 + quad * 4 + reg;
                if (gm < N_NODES) {
                    float v = acc[rt][ct][reg] + bb;
                    f16 h = (f16)v;
                    dh[(size_t)gm * H0D + colbase + n] = h;
                    dl[(size_t)gm * H0D + colbase + n] = (f16)(v - (float)h);
                }
            }
    }
}

// ---------------------------------------------------------------------------
// K3 (screen pass, 1-term, f16 gather, register-B, A-only LDS):
// h1 = relu(Ph[s]+Qh[d]); h = relu(h1@W1h+b1); lk + logits (~4e-4-class).
// atomicMax (lk,t) per segment.
// ---------------------------------------------------------------------------
__global__ __launch_bounds__(256, 3) void k3_f16(
        const f16* __restrict__ Pf, const f16* __restrict__ Qf,
        const f16* __restrict__ W1Bh, const float* __restrict__ b1,
        const float* __restrict__ Wlk, const float* __restrict__ blkp,
        const float* __restrict__ Wa, const float* __restrict__ ba,
        const int* __restrict__ esrc, const int* __restrict__ edst,
        unsigned long long* __restrict__ keys, float* __restrict__ lk_app,
        float* __restrict__ logits) {
    __shared__ f16 Ah[64 * LP];
    __shared__ float redA[64][5], redB[64][5], redC[64][5];
    __shared__ int s_seg[64], s_dst[64];
    const int tid = threadIdx.x;
    const int wave = tid >> 6, lane = tid & 63;
    const int quad = lane >> 4, l15 = lane & 15;
    const int tbase = blockIdx.x * 64;

    if (tid < 64) {
        int t = tbase + tid;
        int s = 0, d = -1;
        if (t < N_EDGES) { s = esrc[t]; d = edst[t]; }
        else if (t < T_TOT) { s = t - N_EDGES; }
        s_seg[tid] = s;
        s_dst[tid] = d;
    }
    __syncthreads();

    const int arow = tid >> 2, akp = tid & 3;
    const int sA = s_seg[arow], dA = s_dst[arow];
    const f16* Prow = Pf + (size_t)sA * H0D + akp * 8;
    const f16* Qrow = Qf + (size_t)(dA >= 0 ? dA : 0) * H0D + akp * 8;
    const bool hasQ = (dA >= 0);
    const f16x8 zero8 = (f16x8)(f16)0;

    f32x4 acc[4][4];
#pragma unroll
    for (int i = 0; i < 4; i++)
#pragma unroll
        for (int j = 0; j < 4; j++) acc[i][j] = (f32x4){0.f, 0.f, 0.f, 0.f};

    f16x8 pa = *(const f16x8*)(Prow);
    f16x8 qa = hasQ ? *(const f16x8*)(Qrow) : zero8;
    f16x8 bf[4], bfn[4];
#pragma unroll
    for (int ct = 0; ct < 4; ct++)
        bf[ct] = *(const f16x8*)(W1Bh + ((size_t)(wave * 64 + ct * 16 + l15)) * 32 + quad * 8);

    for (int c = 0; c < 16; c++) {
        f16x8 hv;
#pragma unroll
        for (int q = 0; q < 8; q++) {
            f16 s = pa[q] + qa[q];
            hv[q] = (s > (f16)0) ? s : (f16)0;
        }
        *(f16x8*)(Ah + arow * LP + akp * 8) = hv;
        if (c + 1 < 16) {
            pa = *(const f16x8*)(Prow + (c + 1) * 32);
            qa = hasQ ? *(const f16x8*)(Qrow + (c + 1) * 32) : zero8;
#pragma unroll
            for (int ct = 0; ct < 4; ct++)
                bfn[ct] = *(const f16x8*)(W1Bh +
                    ((size_t)((c + 1) * 256 + wave * 64 + ct * 16 + l15)) * 32 + quad * 8);
        }
        __syncthreads();
        f16x8 af[4];
#pragma unroll
        for (int rt = 0; rt < 4; rt++)
            af[rt] = *(const f16x8*)(Ah + (rt * 16 + l15) * LP + quad * 8);
#pragma unroll
        for (int rt = 0; rt < 4; rt++)
#pragma unroll
            for (int ct = 0; ct < 4; ct++)
                acc[rt][ct] = __builtin_amdgcn_mfma_f32_16x16x32_f16(
                    af[rt], bf[ct], acc[rt][ct], 0, 0, 0);
        __syncthreads();
#pragma unroll
        for (int ct = 0; ct < 4; ct++) bf[ct] = bfn[ct];
    }

    float wl[4], wa0[4], wa1[4], bb[4];
#pragma unroll
    for (int ct = 0; ct < 4; ct++) {
        int n = wave * 64 + ct * 16 + l15;
        wl[ct] = Wlk[n];
        wa0[ct] = Wa[2 * n];
        wa1[ct] = Wa[2 * n + 1];
        bb[ct] = b1[n];
    }
#pragma unroll
    for (int rt = 0; rt < 4; rt++) {
#pragma unroll
        for (int reg = 0; reg < 4; reg++) {
            float plk = 0.f, p0 = 0.f, p1 = 0.f;
#pragma unroll
            for (int ct = 0; ct < 4; ct++) {
                float h = fmaxf(acc[rt][ct][reg] + bb[ct], 0.f);
                plk = fmaf(h, wl[ct], plk);
                p0 = fmaf(h, wa0[ct], p0);
                p1 = fmaf(h, wa1[ct], p1);
            }
#pragma unroll
            for (int off = 8; off >= 1; off >>= 1) {
                plk += __shfl_xor(plk, off);
                p0 += __shfl_xor(p0, off);
                p1 += __shfl_xor(p1, off);
            }
            if (l15 == 0) {
                int row = rt * 16 + quad * 4 + reg;
                redA[row][wave] = plk;
                redB[row][wave] = p0;
                redC[row][wave] = p1;
            }
        }
    }
    __syncthreads();
    if (tid < 64) {
        int t = tbase + tid;
        if (t < T_TOT) {
            float lk = redA[tid][0] + redA[tid][1] + redA[tid][2] + redA[tid][3] + blkp[0];
            float l0 = redB[tid][0] + redB[tid][1] + redB[tid][2] + redB[tid][3] + ba[0];
            float l1 = redC[tid][0] + redC[tid][1] + redC[tid][2] + redC[tid][3] + ba[1];
            lk_app[t] = lk;
            logits[2 * t] = l0;
            logits[2 * t + 1] = l1;
            unsigned long long key =
                ((unsigned long long)f2ord(lk) << 32) | (unsigned int)t;
            atomicMax(keys + s_seg[tid], key);
        }
    }
}

// ---------------------------------------------------------------------------
// K_GB: gather (a) challengers within MARGIN_LK of their segment best plus the
// segment's approx winner; (b) approx winners whose logit gap < MARGIN_L.
// ---------------------------------------------------------------------------
__global__ void k_gb(const float* __restrict__ lk_app,
                     const unsigned long long* __restrict__ keys,
                     const int* __restrict__ esrc,
                     const float* __restrict__ logits,
                     int* __restrict__ list, int* __restrict__ count) {
    int t = blockIdx.x * 256 + threadIdx.x;
    if (t < T_TOT) {
        int seg = (t < N_EDGES) ? esrc[t] : t - N_EDGES;
        unsigned long long k = keys[seg];
        int tw = (int)(k & 0xFFFFFFFFull);
        if (t != tw) {
            float best = ord2f((unsigned int)(k >> 32));
            if (lk_app[t] >= best - MARGIN_LK) {
                int idx = atomicAdd(count, 2);
                if (idx + 1 < LIST_CAP) { list[idx] = t; list[idx + 1] = tw; }
            }
        }
    }
    if (t < N_NODES) {
        int tw = (int)(keys[t] & 0xFFFFFFFFull);
        float g = fabsf(logits[2 * tw + 1] - logits[2 * tw]);
        if (g < MARGIN_L) {
            int idx = atomicAdd(count, 1);
            if (idx < LIST_CAP) list[idx] = tw;
        }
    }
}

// ---------------------------------------------------------------------------
// K_FIX2 (throughput-shaped MFMA fixup): 64 listed entries per block,
// A = relu((Ph+Pl)+(Qh+Ql)) rebuilt in fp32 then split; 3-term MFMA vs
// W1Ch/W1Cl (error ~2^-22 — the same class P/Q carry). Writes exact
// logits[t] and per-segment (lk,t) atomicMax into keys2.
// ---------------------------------------------------------------------------
__global__ __launch_bounds__(256, 2) void k_fix2(
        const f16* __restrict__ Ph, const f16* __restrict__ Pl,
        const f16* __restrict__ Qh, const f16* __restrict__ Ql,
        const f16* __restrict__ W1Ch, const f16* __restrict__ W1Cl,
        const float* __restrict__ b1, const float* __restrict__ Wlk,
        const float* __restrict__ blkp, const float* __restrict__ Wa,
        const float* __restrict__ ba, const int* __restrict__ esrc,
        const int* __restrict__ edst, const int* __restrict__ list,
        const int* __restrict__ count, unsigned long long* __restrict__ keys2,
        float* __restrict__ logits) {
    __shared__ f16 Ah[64 * LP], Al_[64 * LP];
    __shared__ float redA[64][5], redB[64][5], redC[64][5];
    __shared__ int s_seg[64], s_dst[64], s_t[64];
    const int tid = threadIdx.x;
    const int wave = tid >> 6, lane = tid & 63;
    const int quad = lane >> 4, l15 = lane & 15;
    int cnt = *count;
    if (cnt > LIST_CAP) cnt = LIST_CAP;
    const int nch = (cnt + 63) / 64;

    for (int ch = blockIdx.x; ch < nch; ch += gridDim.x) {
        if (tid < 64) {
            int li = ch * 64 + tid;
            int t = (li < cnt) ? list[li] : -1;
            int s = 0, d = -1;
            if (t >= 0 && t < T_TOT) {
                if (t < N_EDGES) { s = esrc[t]; d = edst[t]; }
                else { s = t - N_EDGES; }
            } else t = -1;
            s_t[tid] = t;
            s_seg[tid] = s;
            s_dst[tid] = d;
        }
        __syncthreads();

        const int arow = tid >> 2, akp = tid & 3;
        const int sA = s_seg[arow], dA = s_dst[arow];
        const f16* ph = Ph + (size_t)sA * H0D + akp * 8;
        const f16* pl = Pl + (size_t)sA * H0D + akp * 8;
        const f16* qh = Qh + (size_t)(dA >= 0 ? dA : 0) * H0D + akp * 8;
        const f16* ql = Ql + (size_t)(dA >= 0 ? dA : 0) * H0D + akp * 8;
        const bool hasQ = (dA >= 0);

        f32x4 acc[4][4];
#pragma unroll
        for (int i = 0; i < 4; i++)
#pragma unroll
            for (int j = 0; j < 4; j++) acc[i][j] = (f32x4){0.f, 0.f, 0.f, 0.f};

        for (int c = 0; c < 16; c++) {
            f16x8 vh = *(const f16x8*)(ph + c * 32);
            f16x8 vl = *(const f16x8*)(pl + c * 32);
            f16x8 wh, wlq;
            if (hasQ) {
                wh = *(const f16x8*)(qh + c * 32);
                wlq = *(const f16x8*)(ql + c * 32);
            }
            f16x8 hv, lv;
#pragma unroll
            for (int q = 0; q < 8; q++) {
                float v = (float)vh[q] + (float)vl[q];
                if (hasQ) v += (float)wh[q] + (float)wlq[q];
                v = fmaxf(v, 0.f);
                f16 h = (f16)v;
                hv[q] = h;
                lv[q] = (f16)(v - (float)h);
            }
            *(f16x8*)(Ah + arow * LP + akp * 8) = hv;
            *(f16x8*)(Al_ + arow * LP + akp * 8) = lv;
            f16x8 bh[4], bl[4];
#pragma unroll
            for (int ct = 0; ct < 4; ct++) {
                size_t o = ((size_t)(c * 256 + wave * 64 + ct * 16 + l15)) * 32 + quad * 8;
                bh[ct] = *(const f16x8*)(W1Ch + o);
                bl[ct] = *(const f16x8*)(W1Cl + o);
            }
            __syncthreads();
            f16x8 afh[4], afl[4];
#pragma unroll
            for (int rt = 0; rt < 4; rt++) {
                afh[rt] = *(const f16x8*)(Ah + (rt * 16 + l15) * LP + quad * 8);
                afl[rt] = *(const f16x8*)(Al_ + (rt * 16 + l15) * LP + quad * 8);
            }
#pragma unroll
            for (int rt = 0; rt < 4; rt++)
#pragma unroll
                for (int ct = 0; ct < 4; ct++) {
                    acc[rt][ct] = __builtin_amdgcn_mfma_f32_16x16x32_f16(
                        afh[rt], bh[ct], acc[rt][ct], 0, 0, 0);
                    acc[rt][ct] = __builtin_amdgcn_mfma_f32_16x16x32_f16(
                        afl[rt], bh[ct], acc[rt][ct], 0, 0, 0);
                    acc[rt][ct] = __builtin_amdgcn_mfma_f32_16x16x32_f16(
                        afh[rt], bl[ct], acc[rt][ct], 0, 0, 0);
                }
            __syncthreads();
        }

        float wl[4], wa0[4], wa1[4], bb[4];
#pragma unroll
        for (int ct = 0; ct < 4; ct++) {
            int n = wave * 64 + ct * 16 + l15;
            wl[ct] = Wlk[n];
            wa0[ct] = Wa[2 * n];
            wa1[ct] = Wa[2 * n + 1];
            bb[ct] = b1[n];
        }
#pragma unroll
        for (int rt = 0; rt < 4; rt++) {
#pragma unroll
            for (int reg = 0; reg < 4; reg++) {
                float plk = 0.f, p0 = 0.f, p1 = 0.f;
#pragma unroll
                for (int ct = 0; ct < 4; ct++) {
                    float h = fmaxf(acc[rt][ct][reg] + bb[ct], 0.f);
                    plk = fmaf(h, wl[ct], plk);
                    p0 = fmaf(h, wa0[ct], p0);
                    p1 = fmaf(h, wa1[ct], p1);
                }
#pragma unroll
                for (int off = 8; off >= 1; off >>= 1) {
                    plk += __shfl_xor(plk, off);
                    p0 += __shfl_xor(p0, off);
                    p1 += __shfl_xor(p1, off);
                }
                if (l15 == 0) {
                    int row = rt * 16 + quad * 4 + reg;
                    redA[row][wave] = plk;
                    redB[row][wave] = p0;
                    redC[row][wave] = p1;
                }
            }
        }
        __syncthreads();
        if (tid < 64) {
            int t = s_t[tid];
            if (t >= 0) {
                float lk = redA[tid][0] + redA[tid][1] + redA[tid][2] + redA[tid][3] + blkp[0];
                float l0 = redB[tid][0] + redB[tid][1] + redB[tid][2] + redB[tid][3] + ba[0];
                float l1 = redC[tid][0] + redC[tid][1] + redC[tid][2] + redC[tid][3] + ba[1];
                logits[2 * t] = l0;
                logits[2 * t + 1] = l1;
                unsigned long long key =
                    ((unsigned long long)f2ord(lk) << 32) | (unsigned int)t;
                atomicMax(keys2 + s_seg[tid], key);
            }
        }
        __syncthreads();
    }
}

// ---------------------------------------------------------------------------
// K4: winner per node (keys2 if exact candidates exist, else approx keys);
// at-bit from logits; last-writer claim (+1 coded).
// ---------------------------------------------------------------------------
__global__ void k4_select(const unsigned long long* __restrict__ keys,
                          const unsigned long long* __restrict__ keys2,
                          const int* __restrict__ edst,
                          const float* __restrict__ logits,
                          int* __restrict__ chosen_arr,
                          int* __restrict__ tgt_writer) {
    int i = blockIdx.x * 256 + threadIdx.x;
    if (i >= N_NODES) return;
    unsigned long long key = keys[i];
    unsigned long long k2v = keys2[i];
    if (k2v != 0ull) key = k2v;
    int t = (int)(key & 0xFFFFFFFFull);
    int chosen = (t < N_EDGES) ? edst[t] : -1;
    float lg0 = logits[2 * t], lg1 = logits[2 * t + 1];
    int at1 = (lg1 > lg0) ? 1 : 0;   // argmax: tie -> index 0
    int c = (chosen >= 0 && at1) ? chosen : -1;
    chosen_arr[i] = c;
    if (c >= 0) atomicMax(tgt_writer + c, i + 1);   // last-write-wins: max i
}

// ---------------------------------------------------------------------------
// K5: winning writers update rows: out[c] = relu(0.5*(Z[i] + Z[c]))
// ---------------------------------------------------------------------------
__global__ void k5_update(const int* __restrict__ chosen_arr,
                          const int* __restrict__ tgt_writer,
                          const float* __restrict__ Z,
                          float* __restrict__ out) {
    int i = blockIdx.x;
    int c = chosen_arr[i];
    if (c < 0 || tgt_writer[c] != i + 1) return;
    int n = threadIdx.x;
    float z = 0.5f * (Z[(size_t)i * E_DIM + n] + Z[(size_t)c * E_DIM + n]);
    out[(size_t)c * E_DIM + n] = fmaxf(z, 0.f);
}

// ---------------------------------------------------------------------------
extern "C" void kernel_launch(void* const* d_in, const int* in_sizes, int n_in,
                              void* d_out, int out_size, void* d_ws,
                              size_t ws_size, hipStream_t stream) {
    const float* feat = (const float*)d_in[0];
    const float* We   = (const float*)d_in[1];
    const float* be   = (const float*)d_in[2];
    const float* W0   = (const float*)d_in[3];
    const float* b0   = (const float*)d_in[4];
    const float* W1   = (const float*)d_in[5];
    const float* b1   = (const float*)d_in[6];
    const float* Wlk  = (const float*)d_in[7];
    const float* blkp = (const float*)d_in[8];
    const float* Wa   = (const float*)d_in[9];
    const float* ba   = (const float*)d_in[10];
    const int* esrc   = (const int*)d_in[11];
    const int* edst   = (const int*)d_in[12];
    float* out = (float*)d_out;

    char* ws = (char*)d_ws;
    size_t off = 0;
    float* Z  = (float*)(ws + off); off += (size_t)N_NODES * E_DIM * 4;
    f16* Ph   = (f16*)(ws + off);   off += (size_t)N_NODES * H0D * 2;
    f16* Pl   = (f16*)(ws + off);   off += (size_t)N_NODES * H0D * 2;
    f16* Qh   = (f16*)(ws + off);   off += (size_t)N_NODES * H0D * 2;
    f16* Ql   = (f16*)(ws + off);   off += (size_t)N_NODES * H0D * 2;
    // ---- contiguous zero-init region ----
    char* zero_base = ws + off;
    unsigned long long* keys  = (unsigned long long*)(ws + off); off += N_NODES * 8;
    unsigned long long* keys2 = (unsigned long long*)(ws + off); off += N_NODES * 8;
    int* tgt_writer = (int*)(ws + off); off += N_NODES * 4;   // +1 encoding, 0 = none
    int* count      = (int*)(ws + off); off += 128;
    size_t zero_bytes = (size_t)((ws + off) - zero_base);
    // -------------------------------------
    float* logits = (float*)(ws + off); off += (size_t)T_TOT * 2 * 4;
    float* lk_app = (float*)(ws + off); off += (size_t)T_TOT * 4;
    int* list     = (int*)(ws + off); off += (size_t)LIST_CAP * 4;
    int* chosen_arr = (int*)(ws + off); off += N_NODES * 4;
    f16* WeC_h = (f16*)(ws + off); off += (size_t)16 * 256 * 32 * 2;
    f16* WeC_l = (f16*)(ws + off); off += (size_t)16 * 256 * 32 * 2;
    f16* W1C_h = (f16*)(ws + off); off += (size_t)16 * 256 * 32 * 2;
    f16* W1C_l = (f16*)(ws + off); off += (size_t)16 * 256 * 32 * 2;
    f16* W0C_h = (f16*)(ws + off); off += (size_t)32 * 256 * 32 * 2;
    f16* W0C_l = (f16*)(ws + off); off += (size_t)32 * 256 * 32 * 2;

    hipMemsetAsync(zero_base, 0, zero_bytes, stream);

    k_prep_all<<<dim3(64), 256, 0, stream>>>(
        We, W1, W0, WeC_h, WeC_l, W1C_h, W1C_l, W0C_h, W0C_l);
    k1_split<<<dim3((N_NODES + 31) / 32), 256, 0, stream>>>(
        feat, WeC_h, WeC_l, be, Z, out);
    k2_split<<<dim3((N_NODES + 63) / 64, 4), 256, 0, stream>>>(
        out, W0C_h, W0C_l, b0, Ph, Pl, Qh, Ql);
    k3_f16<<<dim3((T_TOT + 63) / 64), 256, 0, stream>>>(
        Ph, Qh, W1C_h, b1, Wlk, blkp, Wa, ba, esrc, edst,
        keys, lk_app, logits);
    k_gb<<<dim3((T_TOT + 255) / 256), 256, 0, stream>>>(
        lk_app, keys, esrc, logits, list, count);
    k_fix2<<<dim3(FIX_GRID), 256, 0, stream>>>(
        Ph, Pl, Qh, Ql, W1C_h, W1C_l, b1, Wlk, blkp, Wa, ba,
        esrc, edst, list, count, keys2, logits);
    k4_select<<<dim3((N_NODES + 255) / 256), 256, 0, stream>>>(
        keys, keys2, edst, logits, chosen_arr, tgt_writer);
    k5_update<<<dim3(N_NODES), 256, 0, stream>>>(chosen_arr, tgt_writer, Z, out);
}